// Round 9
// baseline (642.605 us; speedup 1.0000x reference)
//
#include <hip/hip_runtime.h>
#include <hip/hip_bf16.h>
#include <hip/hip_cooperative_groups.h>

namespace cg = cooperative_groups;

// Problem constants
#define BATCH 32
#define LTOT 4096
#define CCH 64
#define NFFT 16
#define HOP 4
#define NF 9            // n_fft/2+1
#define T_FR 1025       // 1 + L/HOP
#define T_ROWS 1032     // padded rows in mag workspace (rows >= 1025 zeroed)
#define ICH 576         // C * NF
#define OCH 512
#define TY 1023         // conv output length
#define OUTW 128

#define GRID_BLKS 1024  // 4 blocks/CU x 256 CUs

typedef __attribute__((ext_vector_type(8))) _Float16 half8;
typedef __attribute__((ext_vector_type(4))) float floatx4;

// cos/sin(n*pi/8) for n = 0..15 — compile-time twiddles.
__device__ constexpr float C16[16] = {
    1.0f,  0.923879533f,  0.707106781f,  0.382683432f,  0.0f, -0.382683432f,
   -0.707106781f, -0.923879533f, -1.0f, -0.923879533f, -0.707106781f,
   -0.382683432f,  0.0f,  0.382683432f,  0.707106781f,  0.923879533f};
__device__ constexpr float S16[16] = {
    0.0f,  0.382683432f,  0.707106781f,  0.923879533f,  1.0f,  0.923879533f,
    0.707106781f,  0.382683432f,  0.0f, -0.382683432f, -0.707106781f,
   -0.923879533f, -1.0f, -0.923879533f, -0.707106781f, -0.382683432f};

#define BM 128
#define BN 128
#define BK 64

__device__ __forceinline__ void async_copy16(const _Float16* g, _Float16* l) {
  __builtin_amdgcn_global_load_lds(
      (const __attribute__((address_space(1))) unsigned int*)g,
      (__attribute__((address_space(3))) unsigned int*)l, 16, 0, 0);
}

// ===========================================================================
// Device helpers shared by fused and split paths (identical arithmetic).
// ===========================================================================
__device__ __forceinline__ void stft_tile(const float* __restrict__ x,
                                          _Float16* __restrict__ m_ws,
                                          float* xs, int b, int t0, int tid) {
  const int l0 = t0 * HOP - 8;
  const float* xb = x + (size_t)b * LTOT * CCH;
#pragma unroll
  for (int it = 0; it < 7; ++it) {
    int e = it * 256 + tid;
    int r = e >> 6, c = e & 63;
    int l = l0 + r;
    if (l < 0) l = -l;
    if (l >= LTOT) l = 2 * LTOT - 2 - l;
    xs[r * 64 + c] = xb[(size_t)l * CCH + c];
  }
  __syncthreads();

  const int c = tid & 63, tq = tid >> 6;
  const int t = t0 + tq;    // t <= 1031 < T_ROWS always
  _Float16* o_ptr = m_ws + ((size_t)b * T_ROWS + t) * ICH + c;
  if (t >= T_FR) {
#pragma unroll
    for (int f = 0; f < NF; ++f) o_ptr[f * 64] = (_Float16)0.0f;
  } else {
    float wx[16];
#pragma unroll
    for (int j = 0; j < 16; ++j)
      wx[j] = xs[(tq * 4 + j) * 64 + c] * (0.5f * (1.0f - C16[j]));
    float s[8], d[8];
#pragma unroll
    for (int j = 1; j < 8; ++j) {
      s[j] = wx[j] + wx[16 - j];
      d[j] = wx[j] - wx[16 - j];
    }
#pragma unroll
    for (int f = 0; f < NF; ++f) {
      float re = wx[0] + ((f & 1) ? -wx[8] : wx[8]);
      float im = 0.0f;
#pragma unroll
      for (int j = 1; j < 8; ++j) {
        re += s[j] * C16[(f * j) & 15];
        im += d[j] * S16[(f * j) & 15];
      }
      o_ptr[f * 64] = (_Float16)sqrtf(re * re + im * im);
    }
  }
}

__device__ __forceinline__ void wrepack_one(const float* __restrict__ weight,
                                            _Float16* __restrict__ wk, int idx) {
  int o = idx / ICH, i = idx - o * ICH;
  int c = i / 9, f = i - c * 9;
  const float* src = weight + (size_t)o * (ICH * 3) + i * 3;
  const size_t dst = (size_t)o * ICH + f * 64 + c;
#pragma unroll
  for (int k = 0; k < 3; ++k)
    wk[(size_t)k * OCH * ICH + dst] = (_Float16)src[k];
}

// conv-as-GEMM tile: global_load_lds width=16 + XOR swizzle, tap-shared B.
// NOTE (R5): never per-element atomics in epilogue (2.3x regression).
__device__ __forceinline__ void gemm_tile(const _Float16* __restrict__ m_ws,
                                          const _Float16* __restrict__ wk,
                                          _Float16* __restrict__ y,
                                          _Float16* as, _Float16* bs,
                                          int b, int o0, int t0, int tid) {
  const int wave = tid >> 6, lane = tid & 63;
  const int wm = wave >> 1, wn = wave & 1;     // 2x2 wave grid

  floatx4 acc[4][4];
#pragma unroll
  for (int mt = 0; mt < 4; ++mt)
#pragma unroll
    for (int nt = 0; nt < 4; ++nt)
      acc[mt][nt] = (floatx4)0.0f;

  const _Float16* mb = m_ws + (size_t)b * T_ROWS * ICH;
  const int frow = lane & 15;
  const int quad = lane >> 4;
  const int l7 = lane & 7;
  const int srow = lane >> 3;
  const int ssrc_off = srow * ICH + (l7 ^ srow) * 8;

  for (int ib = 0; ib < 9; ++ib) {
    const int i0 = ib * 64;
    const _Float16* bg = mb + (size_t)t0 * ICH + i0;

#pragma unroll
    for (int it = 0; it < 4; ++it) {
      const int seg = wave * 4 + it;
      async_copy16(bg + (size_t)(seg * 8) * ICH + ssrc_off, &bs[seg * 512]);
    }
    if (tid < 16)
      async_copy16(bg + (size_t)128 * ICH + ssrc_off, &bs[128 * 64]);

#pragma unroll
    for (int ksh = 0; ksh < 3; ++ksh) {
      const _Float16* ag = wk + ((size_t)ksh * OCH + o0) * ICH + i0;
#pragma unroll
      for (int it = 0; it < 4; ++it) {
        const int seg = wave * 4 + it;
        async_copy16(ag + (size_t)(seg * 8) * ICH + ssrc_off, &as[seg * 512]);
      }
      __syncthreads();

      const int rb7 = (frow + ksh) & 7;
#pragma unroll
      for (int kk2 = 0; kk2 < 2; ++kk2) {
        const int jj = kk2 * 4 + quad;
        const int coffA = ((jj ^ l7) << 3);
        const int coffB = ((jj ^ rb7) << 3);
        half8 af[4], bf[4];
#pragma unroll
        for (int mt = 0; mt < 4; ++mt)
          af[mt] = *(const half8*)(&as[(wm * 64 + mt * 16 + frow) * 64 + coffA]);
#pragma unroll
        for (int nt = 0; nt < 4; ++nt)
          bf[nt] = *(const half8*)(
              &bs[(wn * 64 + nt * 16 + frow + ksh) * 64 + coffB]);
#pragma unroll
        for (int mt = 0; mt < 4; ++mt)
#pragma unroll
          for (int nt = 0; nt < 4; ++nt)
            acc[mt][nt] = __builtin_amdgcn_mfma_f32_16x16x32_f16(
                bf[nt], af[mt], acc[mt][nt], 0, 0, 0);
      }
      __syncthreads();
    }
  }

  // epilogue: y[b][t][o] fp16, t padded to 1024 rows
  const int col = lane & 15;
  _Float16* yb = y + (((size_t)b << 10)) * OCH;
#pragma unroll
  for (int mt = 0; mt < 4; ++mt) {
    const int o = o0 + wm * 64 + mt * 16 + col;
#pragma unroll
    for (int nt = 0; nt < 4; ++nt) {
      const int tb = t0 + wn * 64 + nt * 16 + quad * 4;
#pragma unroll
      for (int r = 0; r < 4; ++r) {
        const int t = tb + r;
        if (t < TY) yb[(size_t)t * OCH + o] = (_Float16)acc[mt][nt][r];
      }
    }
  }
}

__device__ __forceinline__ void pool_unit(const _Float16* __restrict__ y,
                                          const float* __restrict__ bias,
                                          float* __restrict__ out, int unit) {
  const int b = unit >> 13;
  const int w = (unit >> 6) & 127;
  const int o = (unit & 63) * 8;
  const int start = (w * TY) >> 7;
  const int end = ((w + 1) * TY + 127) >> 7;
  const _Float16* yb = y + (((size_t)b << 10)) * OCH;
  float s[8];
#pragma unroll
  for (int i = 0; i < 8; ++i) s[i] = 0.0f;
  for (int t = start; t < end; ++t) {
    half8 v = *(const half8*)(yb + (size_t)t * OCH + o);
#pragma unroll
    for (int i = 0; i < 8; ++i) s[i] += (float)v[i];
  }
  const float inv = 1.0f / (float)(end - start);
  float* op = out + ((size_t)b * OUTW + w) * OCH + o;
  floatx4 r0, r1;
#pragma unroll
  for (int i = 0; i < 4; ++i) r0[i] = s[i] * inv + bias[o + i];
#pragma unroll
  for (int i = 0; i < 4; ++i) r1[i] = s[4 + i] * inv + bias[o + 4 + i];
  *(floatx4*)(op) = r0;
  *(floatx4*)(op + 4) = r1;
}

// ===========================================================================
// Path A: single cooperative kernel (stft+wrepack -> sync -> GEMM -> sync ->
// pool). Launched with fallback: if hipLaunchCooperativeKernel is rejected
// (R8: it failed silently -> all-zero output), Path B runs instead.
// ===========================================================================
__global__ __launch_bounds__(256, 4) void fused_kernel(
    const float* __restrict__ x, const float* __restrict__ weight,
    const float* __restrict__ bias, float* __restrict__ out,
    _Float16* __restrict__ m_ws, _Float16* __restrict__ wk,
    _Float16* __restrict__ y) {
  cg::grid_group grid = cg::this_grid();
  const int tid = threadIdx.x;
  const int blk = blockIdx.x;

  __shared__ __align__(16) char smem[33280];
  float* xs = (float*)smem;                       // 28*64 floats (7 KB)
  _Float16* as = (_Float16*)smem;                 // BM*BK halves (16 KB)
  _Float16* bs = (_Float16*)(smem + BM * BK * 2); // (BN+2)*BK halves

  for (int idx = blk * 256 + tid; idx < OCH * ICH; idx += GRID_BLKS * 256)
    wrepack_one(weight, wk, idx);

  for (int tile = blk; tile < 258 * BATCH; tile += GRID_BLKS) {
    const int b = tile / 258;
    const int t0 = (tile - b * 258) * 4;
    __syncthreads();   // protect xs from previous iteration's readers
    stft_tile(x, m_ws, xs, b, t0, tid);
  }

  __threadfence();
  grid.sync();

  __syncthreads();     // xs -> as/bs reuse boundary
  gemm_tile(m_ws, wk, y, as, bs, blk >> 5, ((blk >> 3) & 3) * BM,
            (blk & 7) * BN, tid);

  __threadfence();
  grid.sync();

  pool_unit(y, bias, out, blk * 256 + tid);
}

// ===========================================================================
// Path B: the R7 four-kernel pipeline (known-good 154.6 us), same helpers.
// ===========================================================================
__global__ __launch_bounds__(256) void stft_kernel(const float* __restrict__ x,
                                                   _Float16* __restrict__ m_ws) {
  __shared__ float xs[28 * 64];
  stft_tile(x, m_ws, xs, blockIdx.y, blockIdx.x * 4, threadIdx.x);
}

__global__ __launch_bounds__(256) void wrepack_kernel(const float* __restrict__ w,
                                                      _Float16* __restrict__ wk) {
  int idx = blockIdx.x * 256 + threadIdx.x;
  if (idx < OCH * ICH) wrepack_one(w, wk, idx);
}

__global__ __launch_bounds__(256, 4) void conv_gemm_kernel(
    const _Float16* __restrict__ m_ws, const _Float16* __restrict__ wk,
    _Float16* __restrict__ y) {
  __shared__ _Float16 as[BM * BK];
  __shared__ _Float16 bs[(BN + 2) * BK];
  gemm_tile(m_ws, wk, y, as, bs, blockIdx.z, blockIdx.y * BM, blockIdx.x * BN,
            threadIdx.x);
}

__global__ __launch_bounds__(256) void pool_kernel(const _Float16* __restrict__ y,
                                                   const float* __restrict__ bias,
                                                   float* __restrict__ out) {
  pool_unit(y, bias, out, blockIdx.x * 256 + threadIdx.x);
}

// ---------------------------------------------------------------------------
extern "C" void kernel_launch(void* const* d_in, const int* in_sizes, int n_in,
                              void* d_out, int out_size, void* d_ws, size_t ws_size,
                              hipStream_t stream) {
  const float* x = (const float*)d_in[0];       // [32, 4096, 64]
  const float* weight = (const float*)d_in[1];  // [512, 576, 3]
  const float* bias = (const float*)d_in[2];    // [512]
  float* out = (float*)d_out;                   // [32, 128, 512]

  char* ws = (char*)d_ws;
  const size_t m_bytes = (size_t)BATCH * T_ROWS * ICH * sizeof(_Float16);  // 38,043,648
  const size_t w_bytes = (size_t)3 * OCH * ICH * sizeof(_Float16);         // 1,769,472
  _Float16* m_ws = (_Float16*)ws;
  _Float16* wk = (_Float16*)(ws + m_bytes);
  _Float16* y = (_Float16*)(ws + m_bytes + w_bytes);  // [32][1024][512] fp16

  void* args[] = {(void*)&x, (void*)&weight, (void*)&bias, (void*)&out,
                  (void*)&m_ws, (void*)&wk, (void*)&y};
  hipError_t err = hipLaunchCooperativeKernel(
      (const void*)fused_kernel, dim3(GRID_BLKS), dim3(256), args, 0, stream);
  if (err != hipSuccess) {
    // Fallback: R7 four-kernel pipeline (identical arithmetic).
    hipLaunchKernelGGL(stft_kernel, dim3(T_ROWS / 4, BATCH), dim3(256), 0,
                       stream, x, m_ws);
    hipLaunchKernelGGL(wrepack_kernel, dim3((OCH * ICH + 255) / 256), dim3(256),
                       0, stream, weight, wk);
    hipLaunchKernelGGL(conv_gemm_kernel, dim3(8, 4, BATCH), dim3(256), 0,
                       stream, m_ws, wk, y);
    hipLaunchKernelGGL(pool_kernel, dim3(OUTW * BATCH / 4), dim3(256), 0,
                       stream, y, bias, out);
  }
}

// Round 10
// 242.763 us; speedup vs baseline: 2.6470x; 2.6470x over previous
//
#include <hip/hip_runtime.h>
#include <hip/hip_bf16.h>

// Problem constants
#define BATCH 32
#define LTOT 4096
#define CCH 64
#define NFFT 16
#define HOP 4
#define NF 9            // n_fft/2+1
#define T_FR 1025       // 1 + L/HOP
#define T_ROWS 1032     // padded rows in mag workspace (rows >= 1025 zeroed)
#define ICH 576         // C * NF
#define OCH 512
#define TY 1023         // conv output length
#define OUTW 128

typedef __attribute__((ext_vector_type(8))) _Float16 half8;
typedef __attribute__((ext_vector_type(4))) float floatx4;

// cos/sin(n*pi/8) for n = 0..15 — compile-time twiddles.
__device__ constexpr float C16[16] = {
    1.0f,  0.923879533f,  0.707106781f,  0.382683432f,  0.0f, -0.382683432f,
   -0.707106781f, -0.923879533f, -1.0f, -0.923879533f, -0.707106781f,
   -0.382683432f,  0.0f,  0.382683432f,  0.707106781f,  0.923879533f};
__device__ constexpr float S16[16] = {
    0.0f,  0.382683432f,  0.707106781f,  0.923879533f,  1.0f,  0.923879533f,
    0.707106781f,  0.382683432f,  0.0f, -0.382683432f, -0.707106781f,
   -0.923879533f, -1.0f, -0.923879533f, -0.707106781f, -0.382683432f};

#define BM 128
#define BN 128
#define BK 64

__device__ __forceinline__ void async_copy16(const _Float16* g, _Float16* l) {
  __builtin_amdgcn_global_load_lds(
      (const __attribute__((address_space(1))) unsigned int*)g,
      (__attribute__((address_space(3))) unsigned int*)l, 16, 0, 0);
}

// ---------------------------------------------------------------------------
// Kernel 1: STFT magnitude + weight repack (merged — one fewer launch gap).
// x [B,L,C] fp32 -> m_ws [b][t][f*64+c] fp16 (f-major i-permutation, shared
// with the weight repack so the conv reduction is a pure GEMM over i).
// Folded real DFT (j<->16-j symmetry), constexpr twiddles.
// wrepack: fp32 [O][I][K=3] -> fp16 wk[k][o][f*64+c]; first 1152 blocks'
// threads each handle one (o,i).
// block = 256 = 64 c x 4 t; grid = (258 t-tiles, 32 b)
// ---------------------------------------------------------------------------
__global__ __launch_bounds__(256) void stft_wrepack_kernel(
    const float* __restrict__ x, const float* __restrict__ weight,
    _Float16* __restrict__ m_ws, _Float16* __restrict__ wk) {
  const int b = blockIdx.y;
  const int t0 = blockIdx.x * 4;
  const int tid = threadIdx.x;

  // ---- weight repack slice (independent of stft work) ----
  const int gid = (b * 258 + blockIdx.x) * 256 + tid;
  if (gid < OCH * ICH) {
    int o = gid / ICH, i = gid - o * ICH;
    int c = i / 9, f = i - c * 9;
    const float* src = weight + (size_t)o * (ICH * 3) + i * 3;
    const size_t dst = (size_t)o * ICH + f * 64 + c;
#pragma unroll
    for (int k = 0; k < 3; ++k)
      wk[(size_t)k * OCH * ICH + dst] = (_Float16)src[k];
  }

  // ---- stft tile ----
  __shared__ float xs[28 * 64];   // frames for 4 t: 4*4+12 = 28 rows of x
  const int l0 = t0 * HOP - 8;
  const float* xb = x + (size_t)b * LTOT * CCH;
#pragma unroll
  for (int it = 0; it < 7; ++it) {
    int e = it * 256 + tid;
    int r = e >> 6, c = e & 63;
    int l = l0 + r;
    if (l < 0) l = -l;
    if (l >= LTOT) l = 2 * LTOT - 2 - l;
    xs[r * 64 + c] = xb[(size_t)l * CCH + c];
  }
  __syncthreads();

  const int c = tid & 63, tq = tid >> 6;
  const int t = t0 + tq;    // t <= 1031 < T_ROWS
  _Float16* o_ptr = m_ws + ((size_t)b * T_ROWS + t) * ICH + c;
  if (t >= T_FR) {
#pragma unroll
    for (int f = 0; f < NF; ++f) o_ptr[f * 64] = (_Float16)0.0f;
    return;
  }
  float wx[16];
#pragma unroll
  for (int j = 0; j < 16; ++j)
    wx[j] = xs[(tq * 4 + j) * 64 + c] * (0.5f * (1.0f - C16[j]));
  float s[8], d[8];
#pragma unroll
  for (int j = 1; j < 8; ++j) {
    s[j] = wx[j] + wx[16 - j];
    d[j] = wx[j] - wx[16 - j];
  }
#pragma unroll
  for (int f = 0; f < NF; ++f) {
    float re = wx[0] + ((f & 1) ? -wx[8] : wx[8]);
    float im = 0.0f;
#pragma unroll
    for (int j = 1; j < 8; ++j) {
      re += s[j] * C16[(f * j) & 15];
      im += d[j] * S16[(f * j) & 15];
    }
    o_ptr[f * 64] = (_Float16)sqrtf(re * re + im * im);
  }
}

// ---------------------------------------------------------------------------
// Kernel 2: conv-as-GEMM.  y[b][t][o] = sum_k sum_i wk[k][o][i]*m[b][t+k][i]
// B (mag rows) staged via global_load_lds width=16 + XOR swizzle, ONCE per
// i-block (tap-shared, rows t0..t0+129). A (weights) read DIRECTLY from
// global as half8 fragments — wk is 1.7 MB, L2-resident per XCD — which
// deletes A staging and cuts barriers 54 -> 18 (2 per ib), letting
// buffer_loads interleave with MFMA instead of draining at each barrier.
// NOTE (R5): no per-element atomics in epilogue (2.3x regression).
// NOTE (R9): no cooperative grid.sync fusion (3.7x regression — cross-XCD
// sync cost dwarfs launch gaps).
// grid = (8 t-tiles, 4 o-tiles, 32 b), block 256 (4 waves, 2x2).
// ---------------------------------------------------------------------------
__global__ __launch_bounds__(256, 4) void conv_gemm_kernel(
    const _Float16* __restrict__ m_ws, const _Float16* __restrict__ wk,
    _Float16* __restrict__ y) {
  const int b = blockIdx.z;
  const int o0 = blockIdx.y * BM;
  const int t0 = blockIdx.x * BN;
  const int tid = threadIdx.x;
  const int wave = tid >> 6, lane = tid & 63;
  const int wm = wave >> 1, wn = wave & 1;     // 2x2 wave grid

  __shared__ _Float16 bs[(BN + 2) * BK];       // 16.25 KB (B rows t0..t0+129)

  floatx4 acc[4][4];
#pragma unroll
  for (int mt = 0; mt < 4; ++mt)
#pragma unroll
    for (int nt = 0; nt < 4; ++nt)
      acc[mt][nt] = (floatx4)0.0f;

  const _Float16* mb = m_ws + (size_t)b * T_ROWS * ICH;
  const int frow = lane & 15;
  const int quad = lane >> 4;
  const int l7 = lane & 7;
  const int srow = lane >> 3;
  const int ssrc_off = srow * ICH + (l7 ^ srow) * 8;

  // A fragment row pointers (o side): row = o0 + wm*64 + mt*16 + frow
  const _Float16* arow[4];
#pragma unroll
  for (int mt = 0; mt < 4; ++mt)
    arow[mt] = wk + (size_t)(o0 + wm * 64 + mt * 16 + frow) * ICH + quad * 8;

  for (int ib = 0; ib < 9; ++ib) {
    const int i0 = ib * 64;
    const _Float16* bg = mb + (size_t)t0 * ICH + i0;

    // stage B rows t0 .. t0+129 (16 full 8-row segments + one 2-row partial)
#pragma unroll
    for (int it = 0; it < 4; ++it) {
      const int seg = wave * 4 + it;
      async_copy16(bg + (size_t)(seg * 8) * ICH + ssrc_off, &bs[seg * 512]);
    }
    if (tid < 16)
      async_copy16(bg + (size_t)128 * ICH + ssrc_off, &bs[128 * 64]);
    __syncthreads();   // drains vmcnt + barrier (B ready)

#pragma unroll
    for (int ksh = 0; ksh < 3; ++ksh) {
      // A fragments straight from L2 (16B-aligned half8 each)
      half8 af[4][2];
      const size_t abase = (size_t)ksh * (OCH * ICH) + i0;
#pragma unroll
      for (int mt = 0; mt < 4; ++mt)
#pragma unroll
        for (int kk2 = 0; kk2 < 2; ++kk2)
          af[mt][kk2] = *(const half8*)(arow[mt] + abase + kk2 * 32);

      const int rb7 = (frow + ksh) & 7;
#pragma unroll
      for (int kk2 = 0; kk2 < 2; ++kk2) {
        const int jj = kk2 * 4 + quad;
        const int coffB = ((jj ^ rb7) << 3);
        half8 bf[4];
#pragma unroll
        for (int nt = 0; nt < 4; ++nt)
          bf[nt] = *(const half8*)(
              &bs[(wn * 64 + nt * 16 + frow + ksh) * 64 + coffB]);
        // first operand = t-fragment => D row (quad*4+reg) = t, D col = o
#pragma unroll
        for (int mt = 0; mt < 4; ++mt)
#pragma unroll
          for (int nt = 0; nt < 4; ++nt)
            acc[mt][nt] = __builtin_amdgcn_mfma_f32_16x16x32_f16(
                bf[nt], af[mt][kk2], acc[mt][nt], 0, 0, 0);
      }
    }
    __syncthreads();   // all taps done before next ib restages bs
  }

  // epilogue: y[b][t][o] fp16, t padded to 1024 rows of OCH halves
  const int col = lane & 15;
  _Float16* yb = y + (((size_t)b << 10)) * OCH;
#pragma unroll
  for (int mt = 0; mt < 4; ++mt) {
    const int o = o0 + wm * 64 + mt * 16 + col;
#pragma unroll
    for (int nt = 0; nt < 4; ++nt) {
      const int tb = t0 + wn * 64 + nt * 16 + quad * 4;
#pragma unroll
      for (int r = 0; r < 4; ++r) {
        const int t = tb + r;
        if (t < TY) yb[(size_t)t * OCH + o] = (_Float16)acc[mt][nt][r];
      }
    }
  }
}

// ---------------------------------------------------------------------------
// Kernel 3: adaptive avg pool (overlapping torch bins) + bias, half8 wide.
// out[b][w][o] = bias[o] + mean_{t in bin(w)} y[b][t][o]
// one (b, w, o-octet) per thread: 32*128*64 = 262144 = 1024 blocks x 256.
// ---------------------------------------------------------------------------
__global__ __launch_bounds__(256) void pool_kernel(const _Float16* __restrict__ y,
                                                   const float* __restrict__ bias,
                                                   float* __restrict__ out) {
  const int unit = blockIdx.x * 256 + threadIdx.x;
  const int b = unit >> 13;
  const int w = (unit >> 6) & 127;
  const int o = (unit & 63) * 8;
  const int start = (w * TY) >> 7;
  const int end = ((w + 1) * TY + 127) >> 7;
  const _Float16* yb = y + (((size_t)b << 10)) * OCH;
  float s[8];
#pragma unroll
  for (int i = 0; i < 8; ++i) s[i] = 0.0f;
  for (int t = start; t < end; ++t) {
    half8 v = *(const half8*)(yb + (size_t)t * OCH + o);
#pragma unroll
    for (int i = 0; i < 8; ++i) s[i] += (float)v[i];
  }
  const float inv = 1.0f / (float)(end - start);
  float* op = out + ((size_t)b * OUTW + w) * OCH + o;
  floatx4 r0, r1;
#pragma unroll
  for (int i = 0; i < 4; ++i) r0[i] = s[i] * inv + bias[o + i];
#pragma unroll
  for (int i = 0; i < 4; ++i) r1[i] = s[4 + i] * inv + bias[o + 4 + i];
  *(floatx4*)(op) = r0;
  *(floatx4*)(op + 4) = r1;
}

// ---------------------------------------------------------------------------
extern "C" void kernel_launch(void* const* d_in, const int* in_sizes, int n_in,
                              void* d_out, int out_size, void* d_ws, size_t ws_size,
                              hipStream_t stream) {
  const float* x = (const float*)d_in[0];       // [32, 4096, 64]
  const float* weight = (const float*)d_in[1];  // [512, 576, 3]
  const float* bias = (const float*)d_in[2];    // [512]
  float* out = (float*)d_out;                   // [32, 128, 512]

  char* ws = (char*)d_ws;
  const size_t m_bytes = (size_t)BATCH * T_ROWS * ICH * sizeof(_Float16);  // 38,043,648
  const size_t w_bytes = (size_t)3 * OCH * ICH * sizeof(_Float16);         // 1,769,472
  _Float16* m_ws = (_Float16*)ws;
  _Float16* wk = (_Float16*)(ws + m_bytes);
  _Float16* y = (_Float16*)(ws + m_bytes + w_bytes);  // [32][1024][512] fp16

  hipLaunchKernelGGL(stft_wrepack_kernel, dim3(258, BATCH), dim3(256), 0,
                     stream, x, weight, m_ws, wk);
  hipLaunchKernelGGL(conv_gemm_kernel, dim3(8, 4, BATCH), dim3(256), 0, stream,
                     m_ws, wk, y);
  hipLaunchKernelGGL(pool_kernel, dim3(OUTW * BATCH / 4), dim3(256), 0, stream,
                     y, bias, out);
}

// Round 11
// 159.947 us; speedup vs baseline: 4.0176x; 1.5178x over previous
//
#include <hip/hip_runtime.h>
#include <hip/hip_bf16.h>

// Problem constants
#define BATCH 32
#define LTOT 4096
#define CCH 64
#define NFFT 16
#define HOP 4
#define NF 9            // n_fft/2+1
#define T_FR 1025       // 1 + L/HOP
#define T_ROWS 1032     // padded rows in mag workspace (rows >= 1025 zeroed)
#define ICH 576         // C * NF
#define OCH 512
#define TY 1023         // conv output length
#define OUTW 128

typedef __attribute__((ext_vector_type(8))) _Float16 half8;
typedef __attribute__((ext_vector_type(4))) float floatx4;

// cos/sin(n*pi/8) for n = 0..15 — compile-time twiddles.
__device__ constexpr float C16[16] = {
    1.0f,  0.923879533f,  0.707106781f,  0.382683432f,  0.0f, -0.382683432f,
   -0.707106781f, -0.923879533f, -1.0f, -0.923879533f, -0.707106781f,
   -0.382683432f,  0.0f,  0.382683432f,  0.707106781f,  0.923879533f};
__device__ constexpr float S16[16] = {
    0.0f,  0.382683432f,  0.707106781f,  0.923879533f,  1.0f,  0.923879533f,
    0.707106781f,  0.382683432f,  0.0f, -0.382683432f, -0.707106781f,
   -0.923879533f, -1.0f, -0.923879533f, -0.707106781f, -0.382683432f};

#define BM 128
#define BN 128
#define BK 64

__device__ __forceinline__ void async_copy16(const _Float16* g, _Float16* l) {
  __builtin_amdgcn_global_load_lds(
      (const __attribute__((address_space(1))) unsigned int*)g,
      (__attribute__((address_space(3))) unsigned int*)l, 16, 0, 0);
}

// ---------------------------------------------------------------------------
// Kernel 1: STFT magnitude + weight repack (merged).
// x [B,L,C] fp32 -> m_ws [b][t][f*64+c] fp16 (f-major i-permutation, shared
// with the weight repack so the conv reduction is a pure GEMM over i).
// Folded real DFT (j<->16-j symmetry), constexpr twiddles.
// block = 256 = 64 c x 4 t; grid = (258 t-tiles, 32 b)
// ---------------------------------------------------------------------------
__global__ __launch_bounds__(256) void stft_wrepack_kernel(
    const float* __restrict__ x, const float* __restrict__ weight,
    _Float16* __restrict__ m_ws, _Float16* __restrict__ wk) {
  const int b = blockIdx.y;
  const int t0 = blockIdx.x * 4;
  const int tid = threadIdx.x;

  // ---- weight repack slice (independent of stft work) ----
  const int gid = (b * 258 + blockIdx.x) * 256 + tid;
  if (gid < OCH * ICH) {
    int o = gid / ICH, i = gid - o * ICH;
    int c = i / 9, f = i - c * 9;
    const float* src = weight + (size_t)o * (ICH * 3) + i * 3;
    const size_t dst = (size_t)o * ICH + f * 64 + c;
#pragma unroll
    for (int k = 0; k < 3; ++k)
      wk[(size_t)k * OCH * ICH + dst] = (_Float16)src[k];
  }

  // ---- stft tile ----
  __shared__ float xs[28 * 64];   // frames for 4 t: 4*4+12 = 28 rows of x
  const int l0 = t0 * HOP - 8;
  const float* xb = x + (size_t)b * LTOT * CCH;
#pragma unroll
  for (int it = 0; it < 7; ++it) {
    int e = it * 256 + tid;
    int r = e >> 6, c = e & 63;
    int l = l0 + r;
    if (l < 0) l = -l;
    if (l >= LTOT) l = 2 * LTOT - 2 - l;
    xs[r * 64 + c] = xb[(size_t)l * CCH + c];
  }
  __syncthreads();

  const int c = tid & 63, tq = tid >> 6;
  const int t = t0 + tq;    // t <= 1031 < T_ROWS
  _Float16* o_ptr = m_ws + ((size_t)b * T_ROWS + t) * ICH + c;
  if (t >= T_FR) {
#pragma unroll
    for (int f = 0; f < NF; ++f) o_ptr[f * 64] = (_Float16)0.0f;
    return;
  }
  float wx[16];
#pragma unroll
  for (int j = 0; j < 16; ++j)
    wx[j] = xs[(tq * 4 + j) * 64 + c] * (0.5f * (1.0f - C16[j]));
  float s[8], d[8];
#pragma unroll
  for (int j = 1; j < 8; ++j) {
    s[j] = wx[j] + wx[16 - j];
    d[j] = wx[j] - wx[16 - j];
  }
#pragma unroll
  for (int f = 0; f < NF; ++f) {
    float re = wx[0] + ((f & 1) ? -wx[8] : wx[8]);
    float im = 0.0f;
#pragma unroll
    for (int j = 1; j < 8; ++j) {
      re += s[j] * C16[(f * j) & 15];
      im += d[j] * S16[(f * j) & 15];
    }
    o_ptr[f * 64] = (_Float16)sqrtf(re * re + im * im);
  }
}

// ---------------------------------------------------------------------------
// Kernel 2: conv-as-GEMM (R7 structure — known-good 57 us, 43% of µbench
// MFMA ceiling). global_load_lds width=16 + XOR swizzle for BOTH A and B;
// tap-shared B staging (B rows t0..t0+129 staged once per i-block, the 3
// conv taps read LDS at row offset ksh).
//   y[b][t][o] = sum_k sum_i wk[k][o][i] * m[b][t+k][i]
// NOTE (R5): no per-element atomics in epilogue (2.3x regression).
// NOTE (R9): no cooperative grid.sync fusion (3.7x regression).
// NOTE (R10): do NOT read A fragments directly from global/L2 — the B
// stream thrashes the 4 MB XCD L2, A re-fetches miss, y write-lines get
// evicted (WRITE 45->112 MB) and MfmaUtil collapsed 44->15%. A must go
// through LDS via the async DMA queue.
// grid = (8 t-tiles, 4 o-tiles, 32 b), block 256 (4 waves, 2x2).
// ---------------------------------------------------------------------------
__global__ __launch_bounds__(256, 4) void conv_gemm_kernel(
    const _Float16* __restrict__ m_ws, const _Float16* __restrict__ wk,
    _Float16* __restrict__ y) {
  const int b = blockIdx.z;
  const int o0 = blockIdx.y * BM;
  const int t0 = blockIdx.x * BN;
  const int tid = threadIdx.x;
  const int wave = tid >> 6, lane = tid & 63;
  const int wm = wave >> 1, wn = wave & 1;     // 2x2 wave grid

  __shared__ _Float16 as[BM * BK];        // 16 KB   (A: weights, tap-current)
  __shared__ _Float16 bs[(BN + 2) * BK];  // 16.25 KB (B: mag rows t0..t0+129)

  floatx4 acc[4][4];
#pragma unroll
  for (int mt = 0; mt < 4; ++mt)
#pragma unroll
    for (int nt = 0; nt < 4; ++nt)
      acc[mt][nt] = (floatx4)0.0f;

  const _Float16* mb = m_ws + (size_t)b * T_ROWS * ICH;
  const int frow = lane & 15;
  const int quad = lane >> 4;
  const int l7 = lane & 7;
  const int srow = lane >> 3;
  const int ssrc_off = srow * ICH + (l7 ^ srow) * 8;

  for (int ib = 0; ib < 9; ++ib) {
    const int i0 = ib * 64;
    const _Float16* bg = mb + (size_t)t0 * ICH + i0;

    // stage B rows t0 .. t0+129 (16 full 8-row segments + one 2-row partial)
#pragma unroll
    for (int it = 0; it < 4; ++it) {
      const int seg = wave * 4 + it;
      async_copy16(bg + (size_t)(seg * 8) * ICH + ssrc_off, &bs[seg * 512]);
    }
    if (tid < 16)
      async_copy16(bg + (size_t)128 * ICH + ssrc_off, &bs[128 * 64]);

#pragma unroll
    for (int ksh = 0; ksh < 3; ++ksh) {
      // stage A (weights for tap ksh)
      const _Float16* ag = wk + ((size_t)ksh * OCH + o0) * ICH + i0;
#pragma unroll
      for (int it = 0; it < 4; ++it) {
        const int seg = wave * 4 + it;
        async_copy16(ag + (size_t)(seg * 8) * ICH + ssrc_off, &as[seg * 512]);
      }
      __syncthreads();   // drains vmcnt (B once per ib + A) + barrier

      const int rb7 = (frow + ksh) & 7;
#pragma unroll
      for (int kk2 = 0; kk2 < 2; ++kk2) {
        const int jj = kk2 * 4 + quad;
        const int coffA = ((jj ^ l7) << 3);
        const int coffB = ((jj ^ rb7) << 3);
        half8 af[4], bf[4];
#pragma unroll
        for (int mt = 0; mt < 4; ++mt)
          af[mt] = *(const half8*)(&as[(wm * 64 + mt * 16 + frow) * 64 + coffA]);
#pragma unroll
        for (int nt = 0; nt < 4; ++nt)
          bf[nt] = *(const half8*)(
              &bs[(wn * 64 + nt * 16 + frow + ksh) * 64 + coffB]);
        // first operand = t-fragment => D row (quad*4+reg) = t, D col = o
#pragma unroll
        for (int mt = 0; mt < 4; ++mt)
#pragma unroll
          for (int nt = 0; nt < 4; ++nt)
            acc[mt][nt] = __builtin_amdgcn_mfma_f32_16x16x32_f16(
                bf[nt], af[mt], acc[mt][nt], 0, 0, 0);
      }
      __syncthreads();
    }
  }

  // epilogue: y[b][t][o] fp16, t padded to 1024 rows of OCH halves
  const int col = lane & 15;
  _Float16* yb = y + (((size_t)b << 10)) * OCH;
#pragma unroll
  for (int mt = 0; mt < 4; ++mt) {
    const int o = o0 + wm * 64 + mt * 16 + col;
#pragma unroll
    for (int nt = 0; nt < 4; ++nt) {
      const int tb = t0 + wn * 64 + nt * 16 + quad * 4;
#pragma unroll
      for (int r = 0; r < 4; ++r) {
        const int t = tb + r;
        if (t < TY) yb[(size_t)t * OCH + o] = (_Float16)acc[mt][nt][r];
      }
    }
  }
}

// ---------------------------------------------------------------------------
// Kernel 3: adaptive avg pool (overlapping torch bins) + bias, half8 wide.
// out[b][w][o] = bias[o] + mean_{t in bin(w)} y[b][t][o]
// one (b, w, o-octet) per thread: 32*128*64 = 262144 = 1024 blocks x 256.
// ---------------------------------------------------------------------------
__global__ __launch_bounds__(256) void pool_kernel(const _Float16* __restrict__ y,
                                                   const float* __restrict__ bias,
                                                   float* __restrict__ out) {
  const int unit = blockIdx.x * 256 + threadIdx.x;
  const int b = unit >> 13;
  const int w = (unit >> 6) & 127;
  const int o = (unit & 63) * 8;
  const int start = (w * TY) >> 7;
  const int end = ((w + 1) * TY + 127) >> 7;
  const _Float16* yb = y + (((size_t)b << 10)) * OCH;
  float s[8];
#pragma unroll
  for (int i = 0; i < 8; ++i) s[i] = 0.0f;
  for (int t = start; t < end; ++t) {
    half8 v = *(const half8*)(yb + (size_t)t * OCH + o);
#pragma unroll
    for (int i = 0; i < 8; ++i) s[i] += (float)v[i];
  }
  const float inv = 1.0f / (float)(end - start);
  float* op = out + ((size_t)b * OUTW + w) * OCH + o;
  floatx4 r0, r1;
#pragma unroll
  for (int i = 0; i < 4; ++i) r0[i] = s[i] * inv + bias[o + i];
#pragma unroll
  for (int i = 0; i < 4; ++i) r1[i] = s[4 + i] * inv + bias[o + 4 + i];
  *(floatx4*)(op) = r0;
  *(floatx4*)(op + 4) = r1;
}

// ---------------------------------------------------------------------------
extern "C" void kernel_launch(void* const* d_in, const int* in_sizes, int n_in,
                              void* d_out, int out_size, void* d_ws, size_t ws_size,
                              hipStream_t stream) {
  const float* x = (const float*)d_in[0];       // [32, 4096, 64]
  const float* weight = (const float*)d_in[1];  // [512, 576, 3]
  const float* bias = (const float*)d_in[2];    // [512]
  float* out = (float*)d_out;                   // [32, 128, 512]

  char* ws = (char*)d_ws;
  const size_t m_bytes = (size_t)BATCH * T_ROWS * ICH * sizeof(_Float16);  // 38,043,648
  const size_t w_bytes = (size_t)3 * OCH * ICH * sizeof(_Float16);         // 1,769,472
  _Float16* m_ws = (_Float16*)ws;
  _Float16* wk = (_Float16*)(ws + m_bytes);
  _Float16* y = (_Float16*)(ws + m_bytes + w_bytes);  // [32][1024][512] fp16

  hipLaunchKernelGGL(stft_wrepack_kernel, dim3(258, BATCH), dim3(256), 0,
                     stream, x, weight, m_ws, wk);
  hipLaunchKernelGGL(conv_gemm_kernel, dim3(8, 4, BATCH), dim3(256), 0, stream,
                     m_ws, wk, y);
  hipLaunchKernelGGL(pool_kernel, dim3(OUTW * BATCH / 4), dim3(256), 0, stream,
                     y, bias, out);
}

// Round 12
// 150.969 us; speedup vs baseline: 4.2565x; 1.0595x over previous
//
#include <hip/hip_runtime.h>
#include <hip/hip_bf16.h>

// Problem constants
#define BATCH 32
#define LTOT 4096
#define CCH 64
#define NFFT 16
#define HOP 4
#define NF 9            // n_fft/2+1
#define T_FR 1025       // 1 + L/HOP
#define T_ROWS 1032     // padded rows in mag workspace (rows >= 1025 zeroed)
#define ICH 576         // C * NF
#define OCH 512
#define TY 1023         // conv output length
#define OUTW 128

typedef __attribute__((ext_vector_type(8))) _Float16 half8;
typedef __attribute__((ext_vector_type(4))) float floatx4;

// cos/sin(n*pi/8) for n = 0..15 — compile-time twiddles.
__device__ constexpr float C16[16] = {
    1.0f,  0.923879533f,  0.707106781f,  0.382683432f,  0.0f, -0.382683432f,
   -0.707106781f, -0.923879533f, -1.0f, -0.923879533f, -0.707106781f,
   -0.382683432f,  0.0f,  0.382683432f,  0.707106781f,  0.923879533f};
__device__ constexpr float S16[16] = {
    0.0f,  0.382683432f,  0.707106781f,  0.923879533f,  1.0f,  0.923879533f,
    0.707106781f,  0.382683432f,  0.0f, -0.382683432f, -0.707106781f,
   -0.923879533f, -1.0f, -0.923879533f, -0.707106781f, -0.382683432f};

#define BM 128
#define BN 256   // R12: doubled t-extent — A staging amortized over 2x work
#define BK 64

__device__ __forceinline__ void async_copy16(const _Float16* g, _Float16* l) {
  __builtin_amdgcn_global_load_lds(
      (const __attribute__((address_space(1))) unsigned int*)g,
      (__attribute__((address_space(3))) unsigned int*)l, 16, 0, 0);
}

// ---------------------------------------------------------------------------
// Kernel 1: STFT magnitude + weight repack (merged).
// x [B,L,C] fp32 -> m_ws [b][t][f*64+c] fp16 (f-major i-permutation, shared
// with the weight repack so the conv reduction is a pure GEMM over i).
// Folded real DFT (j<->16-j symmetry), constexpr twiddles.
// block = 256 = 64 c x 4 t; grid = (258 t-tiles, 32 b)
// ---------------------------------------------------------------------------
__global__ __launch_bounds__(256) void stft_wrepack_kernel(
    const float* __restrict__ x, const float* __restrict__ weight,
    _Float16* __restrict__ m_ws, _Float16* __restrict__ wk) {
  const int b = blockIdx.y;
  const int t0 = blockIdx.x * 4;
  const int tid = threadIdx.x;

  // ---- weight repack slice (independent of stft work) ----
  const int gid = (b * 258 + blockIdx.x) * 256 + tid;
  if (gid < OCH * ICH) {
    int o = gid / ICH, i = gid - o * ICH;
    int c = i / 9, f = i - c * 9;
    const float* src = weight + (size_t)o * (ICH * 3) + i * 3;
    const size_t dst = (size_t)o * ICH + f * 64 + c;
#pragma unroll
    for (int k = 0; k < 3; ++k)
      wk[(size_t)k * OCH * ICH + dst] = (_Float16)src[k];
  }

  // ---- stft tile ----
  __shared__ float xs[28 * 64];   // frames for 4 t: 4*4+12 = 28 rows of x
  const int l0 = t0 * HOP - 8;
  const float* xb = x + (size_t)b * LTOT * CCH;
#pragma unroll
  for (int it = 0; it < 7; ++it) {
    int e = it * 256 + tid;
    int r = e >> 6, c = e & 63;
    int l = l0 + r;
    if (l < 0) l = -l;
    if (l >= LTOT) l = 2 * LTOT - 2 - l;
    xs[r * 64 + c] = xb[(size_t)l * CCH + c];
  }
  __syncthreads();

  const int c = tid & 63, tq = tid >> 6;
  const int t = t0 + tq;    // t <= 1031 < T_ROWS
  _Float16* o_ptr = m_ws + ((size_t)b * T_ROWS + t) * ICH + c;
  if (t >= T_FR) {
#pragma unroll
    for (int f = 0; f < NF; ++f) o_ptr[f * 64] = (_Float16)0.0f;
    return;
  }
  float wx[16];
#pragma unroll
  for (int j = 0; j < 16; ++j)
    wx[j] = xs[(tq * 4 + j) * 64 + c] * (0.5f * (1.0f - C16[j]));
  float s[8], d[8];
#pragma unroll
  for (int j = 1; j < 8; ++j) {
    s[j] = wx[j] + wx[16 - j];
    d[j] = wx[j] - wx[16 - j];
  }
#pragma unroll
  for (int f = 0; f < NF; ++f) {
    float re = wx[0] + ((f & 1) ? -wx[8] : wx[8]);
    float im = 0.0f;
#pragma unroll
    for (int j = 1; j < 8; ++j) {
      re += s[j] * C16[(f * j) & 15];
      im += d[j] * S16[(f * j) & 15];
    }
    o_ptr[f * 64] = (_Float16)sqrtf(re * re + im * im);
  }
}

// ---------------------------------------------------------------------------
// Kernel 2: conv-as-GEMM, 128(o) x 256(t) tile. global_load_lds width=16 +
// XOR swizzle; tap-shared B staging (rows t0..t0+257 staged once per
// i-block); A (weights, 432 KB/block of staging) now amortized over 2x the
// t-extent -> staged volume per unit work 585 -> 364 KB (-38%), and each
// barrier interval carries 2x the MFMA work (64 MFMA/wave).
// 4 waves, wave grid 2(o) x 2(t-half): each wave 64 o x 128 t, acc[4][8].
//   y[b][t][o] = sum_k sum_i wk[k][o][i] * m[b][t+k][i]
// NOTE (R5): no per-element atomics in epilogue (2.3x regression).
// NOTE (R9): no cooperative grid.sync fusion (3.7x regression).
// NOTE (R10): A must go through LDS via async DMA — direct L2 reads thrash
// the 4 MB XCD L2 (FETCH 27->44 MB, WRITE 45->112 MB, MfmaUtil 44->15%).
// grid = (4 t-tiles, 4 o-tiles, 32 b), block 256.
// ---------------------------------------------------------------------------
__global__ __launch_bounds__(256, 2) void conv_gemm_kernel(
    const _Float16* __restrict__ m_ws, const _Float16* __restrict__ wk,
    _Float16* __restrict__ y) {
  const int b = blockIdx.z;
  const int o0 = blockIdx.y * BM;
  const int t0 = blockIdx.x * BN;
  const int tid = threadIdx.x;
  const int wave = tid >> 6, lane = tid & 63;
  const int wm = wave >> 1, wn = wave & 1;     // 2x2 wave grid (o x t-half)

  __shared__ _Float16 as[BM * BK];        // 16 KB    (A: weights, tap-current)
  __shared__ _Float16 bs[(BN + 2) * BK];  // 32.25 KB (B: mag rows t0..t0+257)

  floatx4 acc[4][8];
#pragma unroll
  for (int mt = 0; mt < 4; ++mt)
#pragma unroll
    for (int nt = 0; nt < 8; ++nt)
      acc[mt][nt] = (floatx4)0.0f;

  const _Float16* mb = m_ws + (size_t)b * T_ROWS * ICH;
  const int frow = lane & 15;
  const int quad = lane >> 4;
  const int l7 = lane & 7;
  const int srow = lane >> 3;
  const int ssrc_off = srow * ICH + (l7 ^ srow) * 8;

  for (int ib = 0; ib < 9; ++ib) {
    const int i0 = ib * 64;
    const _Float16* bg = mb + (size_t)t0 * ICH + i0;

    // stage B rows t0 .. t0+257 (32 full 8-row segments + one 2-row partial)
#pragma unroll
    for (int it = 0; it < 8; ++it) {
      const int seg = wave * 8 + it;
      async_copy16(bg + (size_t)(seg * 8) * ICH + ssrc_off, &bs[seg * 512]);
    }
    if (tid < 16)   // rows 256,257 (t0 max 768 -> row 1025 < T_ROWS)
      async_copy16(bg + (size_t)256 * ICH + ssrc_off, &bs[256 * 64]);

#pragma unroll
    for (int ksh = 0; ksh < 3; ++ksh) {
      // stage A (weights for tap ksh)
      const _Float16* ag = wk + ((size_t)ksh * OCH + o0) * ICH + i0;
#pragma unroll
      for (int it = 0; it < 4; ++it) {
        const int seg = wave * 4 + it;
        async_copy16(ag + (size_t)(seg * 8) * ICH + ssrc_off, &as[seg * 512]);
      }
      __syncthreads();   // drains vmcnt (B once per ib + A) + barrier

      const int rb7 = (frow + ksh) & 7;
#pragma unroll
      for (int kk2 = 0; kk2 < 2; ++kk2) {
        const int jj = kk2 * 4 + quad;
        const int coffA = ((jj ^ l7) << 3);
        const int coffB = ((jj ^ rb7) << 3);
        half8 af[4], bf[8];
#pragma unroll
        for (int mt = 0; mt < 4; ++mt)
          af[mt] = *(const half8*)(&as[(wm * 64 + mt * 16 + frow) * 64 + coffA]);
#pragma unroll
        for (int nt = 0; nt < 8; ++nt)
          bf[nt] = *(const half8*)(
              &bs[(wn * 128 + nt * 16 + frow + ksh) * 64 + coffB]);
        // first operand = t-fragment => D row (quad*4+reg) = t, D col = o
#pragma unroll
        for (int mt = 0; mt < 4; ++mt)
#pragma unroll
          for (int nt = 0; nt < 8; ++nt)
            acc[mt][nt] = __builtin_amdgcn_mfma_f32_16x16x32_f16(
                bf[nt], af[mt], acc[mt][nt], 0, 0, 0);
      }
      __syncthreads();
    }
  }

  // epilogue: y[b][t][o] fp16, t padded to 1024 rows of OCH halves
  const int col = lane & 15;
  _Float16* yb = y + (((size_t)b << 10)) * OCH;
#pragma unroll
  for (int mt = 0; mt < 4; ++mt) {
    const int o = o0 + wm * 64 + mt * 16 + col;
#pragma unroll
    for (int nt = 0; nt < 8; ++nt) {
      const int tb = t0 + wn * 128 + nt * 16 + quad * 4;
#pragma unroll
      for (int r = 0; r < 4; ++r) {
        const int t = tb + r;
        if (t < TY) yb[(size_t)t * OCH + o] = (_Float16)acc[mt][nt][r];
      }
    }
  }
}

// ---------------------------------------------------------------------------
// Kernel 3: adaptive avg pool (overlapping torch bins) + bias, half8 wide.
// out[b][w][o] = bias[o] + mean_{t in bin(w)} y[b][t][o]
// one (b, w, o-octet) per thread: 32*128*64 = 262144 = 1024 blocks x 256.
// ---------------------------------------------------------------------------
__global__ __launch_bounds__(256) void pool_kernel(const _Float16* __restrict__ y,
                                                   const float* __restrict__ bias,
                                                   float* __restrict__ out) {
  const int unit = blockIdx.x * 256 + threadIdx.x;
  const int b = unit >> 13;
  const int w = (unit >> 6) & 127;
  const int o = (unit & 63) * 8;
  const int start = (w * TY) >> 7;
  const int end = ((w + 1) * TY + 127) >> 7;
  const _Float16* yb = y + (((size_t)b << 10)) * OCH;
  float s[8];
#pragma unroll
  for (int i = 0; i < 8; ++i) s[i] = 0.0f;
  for (int t = start; t < end; ++t) {
    half8 v = *(const half8*)(yb + (size_t)t * OCH + o);
#pragma unroll
    for (int i = 0; i < 8; ++i) s[i] += (float)v[i];
  }
  const float inv = 1.0f / (float)(end - start);
  float* op = out + ((size_t)b * OUTW + w) * OCH + o;
  floatx4 r0, r1;
#pragma unroll
  for (int i = 0; i < 4; ++i) r0[i] = s[i] * inv + bias[o + i];
#pragma unroll
  for (int i = 0; i < 4; ++i) r1[i] = s[4 + i] * inv + bias[o + 4 + i];
  *(floatx4*)(op) = r0;
  *(floatx4*)(op + 4) = r1;
}

// ---------------------------------------------------------------------------
extern "C" void kernel_launch(void* const* d_in, const int* in_sizes, int n_in,
                              void* d_out, int out_size, void* d_ws, size_t ws_size,
                              hipStream_t stream) {
  const float* x = (const float*)d_in[0];       // [32, 4096, 64]
  const float* weight = (const float*)d_in[1];  // [512, 576, 3]
  const float* bias = (const float*)d_in[2];    // [512]
  float* out = (float*)d_out;                   // [32, 128, 512]

  char* ws = (char*)d_ws;
  const size_t m_bytes = (size_t)BATCH * T_ROWS * ICH * sizeof(_Float16);  // 38,043,648
  const size_t w_bytes = (size_t)3 * OCH * ICH * sizeof(_Float16);         // 1,769,472
  _Float16* m_ws = (_Float16*)ws;
  _Float16* wk = (_Float16*)(ws + m_bytes);
  _Float16* y = (_Float16*)(ws + m_bytes + w_bytes);  // [32][1024][512] fp16

  hipLaunchKernelGGL(stft_wrepack_kernel, dim3(258, BATCH), dim3(256), 0,
                     stream, x, weight, m_ws, wk);
  hipLaunchKernelGGL(conv_gemm_kernel, dim3(4, 4, BATCH), dim3(256), 0, stream,
                     m_ws, wk, y);
  hipLaunchKernelGGL(pool_kernel, dim3(OUTW * BATCH / 4), dim3(256), 0, stream,
                     y, bias, out);
}